// Round 1
// baseline (389.935 us; speedup 1.0000x reference)
//
#include <hip/hip_runtime.h>
#include <hip/hip_bf16.h>

// Fused QKV projection: qkv = hidden[16384,1024] @ Wqkv[1024,3072] + bias,
// scattered to q/k/v [4,16,4096,64] each, fp32 out.
// R4: port GEMM to the 256x256 8-phase schedule (T1+T2+T3+T4+T5):
//  - BM=BN=256, BK=64, 8 waves (2Mx4N), per-wave 128x64, mfma_32x32x16_bf16
//  - 128 KiB double-buffered LDS, global_load_lds w=16 with pre-swizzled
//    global source; slot p = kq ^ (row&7) over 8 octets (balanced banks)
//  - per K-tile: 4 phases {ds_read || stage pair -> barrier -> lgkmcnt(0)
//    -> setprio(1) 8xMFMA setprio(0) -> barrier}, counted vmcnt(2) once
//    per tile (never 0 in steady state)
//  - bijective XCD swizzle (768 blocks % 8 == 0)

#define M_TOT 16384
#define N_TOT 3072
#define K_TOT 1024

typedef __bf16 bf16x8 __attribute__((ext_vector_type(8)));
typedef float f32x16 __attribute__((ext_vector_type(16)));

#define AS1(p) ((const __attribute__((address_space(1))) void*)(p))
#define AS3(p) ((__attribute__((address_space(3))) void*)(p))

__device__ __forceinline__ unsigned short f2bf(float f) {
    unsigned int u = __builtin_bit_cast(unsigned int, f);
    u += 0x7fffu + ((u >> 16) & 1u);
    return (unsigned short)(u >> 16);
}

// ---- kernel 1: hidden fp32 -> bf16, straight copy (row-major [16384][1024])
__global__ void convert_hidden(const float* __restrict__ x,
                               unsigned short* __restrict__ y, int n4) {
    int i = blockIdx.x * blockDim.x + threadIdx.x;
    int stride = gridDim.x * blockDim.x;
    for (; i < n4; i += stride) {
        float4 v = ((const float4*)x)[i];
        ushort4 o;
        o.x = f2bf(v.x); o.y = f2bf(v.y); o.z = f2bf(v.z); o.w = f2bf(v.w);
        ((ushort4*)y)[i] = o;
    }
}

// ---- kernel 2: W[k][f] fp32 -> Bt[wsel*1024 + f][k] bf16 (transpose), tiled 64x64
__global__ void convert_weights(const float* __restrict__ Wq,
                                const float* __restrict__ Wk,
                                const float* __restrict__ Wv,
                                unsigned short* __restrict__ Bt) {
    __shared__ unsigned short tile[64][65];
    const float* W = (blockIdx.z == 0) ? Wq : (blockIdx.z == 1) ? Wk : Wv;
    int k0 = blockIdx.y * 64;
    int f0 = blockIdx.x * 64;
    int tx = threadIdx.x & 63;
    int ty = threadIdx.x >> 6;  // 0..3
#pragma unroll
    for (int r = 0; r < 16; ++r) {
        int k = ty + r * 4;
        tile[k][tx] = f2bf(W[(size_t)(k0 + k) * 1024 + f0 + tx]);
    }
    __syncthreads();
#pragma unroll
    for (int r = 0; r < 16; ++r) {
        int fr = ty + r * 4;
        Bt[(size_t)(blockIdx.z * 1024 + f0 + fr) * 1024 + k0 + tx] = tile[tx][fr];
    }
}

// ---- kernel 3: 256x256 8-phase GEMM + bias + scatter-to-heads epilogue
// A [16384][1024] bf16 row-major, Bt [3072][1024] bf16 (W^T), out fp32.
// LDS tile layout: [256 rows][64 k] bf16, row stride 128 B = 8 x 16B octets.
// Octet kq of row r lives at slot p = kq ^ (r&7); staging achieves this by
// permuting each lane's *global* source octet (global_load_lds dest stays
// linear: wave-uniform base + lane*16).
__launch_bounds__(512, 2)
__global__ void qkv_gemm(const unsigned short* __restrict__ A,
                         const unsigned short* __restrict__ Bt,
                         const float* __restrict__ bq,
                         const float* __restrict__ bk,
                         const float* __restrict__ bv,
                         float* __restrict__ out) {
    __shared__ __align__(16) unsigned short As[2][16384];  // 2 x 32 KiB
    __shared__ __align__(16) unsigned short Bs[2][16384];  // 2 x 32 KiB

    const int tid  = threadIdx.x;
    const int wave = tid >> 6;
    const int lane = tid & 63;
    const int r5   = lane & 31;   // row within a 32-row MFMA block
    const int half = lane >> 5;   // k-octet select within a k-step

    // bijective XCD swizzle: 768 blocks = 8 XCDs x 96
    const int orig = blockIdx.x;
    const int wg   = (orig & 7) * 96 + (orig >> 3);
    const int bm   = wg & 63;   // 0..63  (M tiles of 256)
    const int bn   = wg >> 6;   // 0..11  (N tiles of 256)

    const int wr = wave >> 2;   // 0..1  -> 128-row half
    const int wc = wave & 3;    // 0..3  -> 64-col quarter

    f32x16 acc[4][2] = {};

    // staging: issue i writes 16B chunks c = i*512 + tid; row = c>>3 =
    // i*64 + (tid>>3), slot = tid&7 -> fetch logical octet kq = slot ^ (row&7).
    const int trow = tid >> 3;                                // 0..63
    const int tkq8 = ((tid & 7) ^ (trow & 7)) * 8;            // element offset
    const unsigned short* gA = A  + (size_t)(bm * 256 + trow) * 1024 + tkq8;
    const unsigned short* gB = Bt + (size_t)(bn * 256 + trow) * 1024 + tkq8;

#define STAGE(i, koff, dstA, dstB)                                              \
    do {                                                                        \
        __builtin_amdgcn_global_load_lds(                                       \
            AS1(gA + (size_t)(i)*65536 + (koff)),                               \
            AS3((dstA) + ((i)*512 + wave * 64) * 8), 16, 0, 0);                 \
        __builtin_amdgcn_global_load_lds(                                       \
            AS1(gB + (size_t)(i)*65536 + (koff)),                               \
            AS3((dstB) + ((i)*512 + wave * 64) * 8), 16, 0, 0);                 \
    } while (0)

    // prologue: stage K-tile 0 into buffer 0 (8 loads)
#pragma unroll
    for (int i = 0; i < 4; ++i) STAGE(i, 0, As[0], Bs[0]);

#pragma unroll 2
    for (int t = 0; t < 16; ++t) {
        const int cur = t & 1;
        const int nxt = cur ^ 1;
        const bool pf = (t < 15);
        const int koff = (t + 1) * 64;
        const unsigned short* Ab = As[cur];
        const unsigned short* Bb = Bs[cur];

#pragma unroll
        for (int ks = 0; ks < 4; ++ks) {
            bf16x8 av[4], bvv[2];
            // read-side swizzle: octet = ks*2 + half, row&7 == r5&7
            const int prd = ((ks * 2 + half) ^ (r5 & 7)) * 8;
            if (ks == 0) {
                // first pair for next tile stays in flight across the wait
                if (pf) STAGE(0, koff, As[nxt], Bs[nxt]);
                if (pf) asm volatile("s_waitcnt vmcnt(2)" ::: "memory");
                else    asm volatile("s_waitcnt vmcnt(0)" ::: "memory");
                __builtin_amdgcn_s_barrier();
                __builtin_amdgcn_sched_barrier(0);  // no ds_read above the wait
#pragma unroll
                for (int ib = 0; ib < 4; ++ib)
                    av[ib] = *(const bf16x8*)&Ab[(wr * 128 + ib * 32 + r5) * 64 + prd];
#pragma unroll
                for (int jb = 0; jb < 2; ++jb)
                    bvv[jb] = *(const bf16x8*)&Bb[(wc * 64 + jb * 32 + r5) * 64 + prd];
            } else {
#pragma unroll
                for (int ib = 0; ib < 4; ++ib)
                    av[ib] = *(const bf16x8*)&Ab[(wr * 128 + ib * 32 + r5) * 64 + prd];
#pragma unroll
                for (int jb = 0; jb < 2; ++jb)
                    bvv[jb] = *(const bf16x8*)&Bb[(wc * 64 + jb * 32 + r5) * 64 + prd];
                if (pf) STAGE(ks, koff, As[nxt], Bs[nxt]);
                __builtin_amdgcn_s_barrier();
            }
            asm volatile("s_waitcnt lgkmcnt(0)" ::: "memory");
            __builtin_amdgcn_sched_barrier(0);  // rule 18: keep MFMA below the wait
            __builtin_amdgcn_s_setprio(1);
#pragma unroll
            for (int ib = 0; ib < 4; ++ib)
#pragma unroll
                for (int jb = 0; jb < 2; ++jb)
                    acc[ib][jb] = __builtin_amdgcn_mfma_f32_32x32x16_bf16(
                        av[ib], bvv[jb], acc[ib][jb], 0, 0, 0);
            __builtin_amdgcn_s_setprio(0);
            __builtin_amdgcn_s_barrier();
        }
    }
#undef STAGE

    // Epilogue: 32x32 C/D mapping col = lane&31, row = (reg&3)+8*(reg>>2)+4*half.
    const int section = bn >> 2;                      // 0,1,2 (q/k/v)
    const int nloc0   = (bn & 3) * 256 + wc * 64;     // col within section
    const float* bias = (section == 0) ? bq : (section == 1) ? bk : bv;
    float* outsec = out + (size_t)section * (4u * 16u * 4096u * 64u);

#pragma unroll
    for (int jb = 0; jb < 2; ++jb) {
        int f = nloc0 + jb * 32 + r5;  // 0..1023 within section
        float bval = bias[f];
        int h = f >> 6, d = f & 63;
        size_t hb = (size_t)h * (4096u * 64u);
#pragma unroll
        for (int ib = 0; ib < 4; ++ib) {
            int mbase = bm * 256 + wr * 128 + ib * 32 + 4 * half;
#pragma unroll
            for (int reg = 0; reg < 16; ++reg) {
                int m = mbase + (reg & 3) + 8 * (reg >> 2);
                int b = m >> 12, s = m & 4095;
                outsec[(size_t)b * (16u * 4096u * 64u) + hb + (size_t)s * 64u + d] =
                    acc[ib][jb][reg] + bval;
            }
        }
    }
}

extern "C" void kernel_launch(void* const* d_in, const int* in_sizes, int n_in,
                              void* d_out, int out_size, void* d_ws, size_t ws_size,
                              hipStream_t stream) {
    const float* hs = (const float*)d_in[0];
    const float* Wq = (const float*)d_in[1];
    const float* bq = (const float*)d_in[2];
    const float* Wk = (const float*)d_in[3];
    const float* bk = (const float*)d_in[4];
    const float* Wv = (const float*)d_in[5];
    const float* bv = (const float*)d_in[6];
    float* out = (float*)d_out;

    unsigned short* Abf  = (unsigned short*)d_ws;            // 16384*1024 bf16 = 32 MiB
    unsigned short* Btbf = Abf + (size_t)M_TOT * K_TOT;      // 3072*1024  bf16 =  6 MiB

    convert_hidden<<<2048, 256, 0, stream>>>(hs, Abf, (M_TOT * K_TOT) / 4);
    convert_weights<<<dim3(16, 16, 3), 256, 0, stream>>>(Wq, Wk, Wv, Btbf);
    qkv_gemm<<<dim3((M_TOT / 256) * (N_TOT / 256)), 512, 0, stream>>>(Abf, Btbf, bq, bk, bv, out);
}

// Round 2
// 372.128 us; speedup vs baseline: 1.0479x; 1.0479x over previous
//
#include <hip/hip_runtime.h>
#include <hip/hip_bf16.h>

// Fused QKV projection: qkv = hidden[16384,1024] @ Wqkv[1024,3072] + bias,
// scattered to q/k/v [4,16,4096,64] each, fp32 out.
// R5: 256x256 tile, BK=64, 8 waves, mfma_32x32x16, but:
//  - only 2 barriers per K-tile (wave-slip overlap instead of lockstep);
//    reads hit buf[cur], stages write buf[nxt] -> no intra-tile hazard
//  - persistent blocks: grid=256, 3 GEMM-tiles each; K-tile 15 stages the
//    NEXT tile's K0, so epilogue stores overlap next prologue loads
//  - 8bm x 4bn supertile per XCD (st = xcd*3+i, bijective over 768 tiles):
//    A-panel working set ~4MB fits XCD L2 -> stage sources are L2 hits
//  - counted vmcnt(2) at tile boundary (2 newest = next tile's chunk 0)

#define M_TOT 16384
#define N_TOT 3072
#define K_TOT 1024

typedef __bf16 bf16x8 __attribute__((ext_vector_type(8)));
typedef float f32x16 __attribute__((ext_vector_type(16)));

#define AS1(p) ((const __attribute__((address_space(1))) void*)(p))
#define AS3(p) ((__attribute__((address_space(3))) void*)(p))

__device__ __forceinline__ unsigned short f2bf(float f) {
    unsigned int u = __builtin_bit_cast(unsigned int, f);
    u += 0x7fffu + ((u >> 16) & 1u);
    return (unsigned short)(u >> 16);
}

// ---- kernel 1: hidden fp32 -> bf16, straight copy (row-major [16384][1024])
__global__ void convert_hidden(const float* __restrict__ x,
                               unsigned short* __restrict__ y, int n4) {
    int i = blockIdx.x * blockDim.x + threadIdx.x;
    int stride = gridDim.x * blockDim.x;
    for (; i < n4; i += stride) {
        float4 v = ((const float4*)x)[i];
        ushort4 o;
        o.x = f2bf(v.x); o.y = f2bf(v.y); o.z = f2bf(v.z); o.w = f2bf(v.w);
        ((ushort4*)y)[i] = o;
    }
}

// ---- kernel 2: W[k][f] fp32 -> Bt[wsel*1024 + f][k] bf16 (transpose), tiled 64x64
__global__ void convert_weights(const float* __restrict__ Wq,
                                const float* __restrict__ Wk,
                                const float* __restrict__ Wv,
                                unsigned short* __restrict__ Bt) {
    __shared__ unsigned short tile[64][65];
    const float* W = (blockIdx.z == 0) ? Wq : (blockIdx.z == 1) ? Wk : Wv;
    int k0 = blockIdx.y * 64;
    int f0 = blockIdx.x * 64;
    int tx = threadIdx.x & 63;
    int ty = threadIdx.x >> 6;  // 0..3
#pragma unroll
    for (int r = 0; r < 16; ++r) {
        int k = ty + r * 4;
        tile[k][tx] = f2bf(W[(size_t)(k0 + k) * 1024 + f0 + tx]);
    }
    __syncthreads();
#pragma unroll
    for (int r = 0; r < 16; ++r) {
        int fr = ty + r * 4;
        Bt[(size_t)(blockIdx.z * 1024 + f0 + fr) * 1024 + k0 + tx] = tile[tx][fr];
    }
}

// ---- kernel 3: persistent 256x256 GEMM + bias + scatter-to-heads epilogue
// A [16384][1024] bf16 row-major, Bt [3072][1024] bf16 (W^T), out fp32.
// LDS tile [256 rows][64 k] bf16, row stride 128 B = 8 x 16B octets; octet
// kq of row r lives at slot kq ^ (r&7) via pre-swizzled global source.
__launch_bounds__(512, 2)
__global__ void qkv_gemm(const unsigned short* __restrict__ A,
                         const unsigned short* __restrict__ Bt,
                         const float* __restrict__ bq,
                         const float* __restrict__ bk,
                         const float* __restrict__ bv,
                         float* __restrict__ out) {
    __shared__ __align__(16) unsigned short As[2][16384];  // 2 x 32 KiB
    __shared__ __align__(16) unsigned short Bs[2][16384];  // 2 x 32 KiB

    const int tid  = threadIdx.x;
    const int wave = tid >> 6;
    const int lane = tid & 63;
    const int r5   = lane & 31;   // row within a 32-row MFMA block
    const int half = lane >> 5;   // k-octet select within a k-step
    const int swr  = r5 & 7;      // read-side swizzle term

    // persistent mapping: 256 blocks x 3 iters -> 768 tiles (64bm x 12bn).
    // supertile = 8bm x 4bn (32 tiles); st = xcd*3 + i in [0,24); bijective.
    const int xcd = blockIdx.x & 7;
    const int j   = blockIdx.x >> 3;  // 0..31
    const int jm  = j & 7;            // bm within supertile
    const int jn  = j >> 3;           // bn within supertile

    const int wr = wave >> 2;   // 0..1  -> 128-row half
    const int wc = wave & 3;    // 0..3  -> 64-col quarter

    // staging: chunk c covers rows c*64..c*64+63; thread tid writes 16B slot
    // (c*512 + tid); row = c*64 + (tid>>3), slot = tid&7 -> fetch octet
    // kq = slot ^ (row&7) from global.
    const int trow = tid >> 3;                      // 0..63
    const int tkq8 = ((tid & 7) ^ (trow & 7)) * 8;  // element offset

    int st = xcd * 3;                       // supertile for i=0
    int bm = (st & 7) * 8 + jm;
    int bn = (st >> 3) * 4 + jn;
    const unsigned short* gA = A  + (size_t)(bm * 256 + trow) * 1024 + tkq8;
    const unsigned short* gB = Bt + (size_t)(bn * 256 + trow) * 1024 + tkq8;

#define STAGE(c)                                                                \
    do {                                                                        \
        __builtin_amdgcn_global_load_lds(AS1(sA + (size_t)(c)*65536),           \
                                         AS3(dA + ((c)*512 + wave * 64) * 8),   \
                                         16, 0, 0);                             \
        __builtin_amdgcn_global_load_lds(AS1(sB + (size_t)(c)*65536),           \
                                         AS3(dB + ((c)*512 + wave * 64) * 8),   \
                                         16, 0, 0);                             \
    } while (0)

    // prologue: stage iter-0 K-tile 0 into buffer 0 (8 loads)
    {
        const unsigned short* sA = gA;
        const unsigned short* sB = gB;
        unsigned short* dA = (unsigned short*)As[0];
        unsigned short* dB = (unsigned short*)Bs[0];
#pragma unroll
        for (int c = 0; c < 4; ++c) STAGE(c);
    }

    for (int i = 0; i < 3; ++i) {
        // next-iter tile (staged during this iter's t=15)
        int bm2 = bm, bn2 = bn;
        const unsigned short *gA2 = gA, *gB2 = gB;
        if (i < 2) {
            int st2 = xcd * 3 + i + 1;
            bm2 = (st2 & 7) * 8 + jm;
            bn2 = (st2 >> 3) * 4 + jn;
            gA2 = A  + (size_t)(bm2 * 256 + trow) * 1024 + tkq8;
            gB2 = Bt + (size_t)(bn2 * 256 + trow) * 1024 + tkq8;
        }

        f32x16 acc[4][2] = {};

#pragma unroll 2
        for (int t = 0; t < 16; ++t) {
            const int cur = t & 1;
            const unsigned short* Ab = As[cur];
            const unsigned short* Bb = Bs[cur];
            unsigned short* dA = (unsigned short*)As[cur ^ 1];
            unsigned short* dB = (unsigned short*)Bs[cur ^ 1];
            const bool stg = (t < 15) || (i < 2);
            const unsigned short* sA = (t < 15) ? gA + (size_t)(t + 1) * 64 : gA2;
            const unsigned short* sB = (t < 15) ? gB + (size_t)(t + 1) * 64 : gB2;

#pragma unroll
            for (int ks = 0; ks < 4; ++ks) {
                bf16x8 av[4], bvv[2];
                const int prd = ((ks * 2 + half) ^ swr) * 8;
                if (ks == 0) {
                    // tile boundary: 2 newest in-flight loads = next tile's
                    // chunk 0; everything older (this tile's 8) must land.
                    if (stg) {
                        STAGE(0);
                        asm volatile("s_waitcnt vmcnt(2)" ::: "memory");
                    } else {
                        asm volatile("s_waitcnt vmcnt(0)" ::: "memory");
                    }
                    __builtin_amdgcn_s_barrier();
                    __builtin_amdgcn_sched_barrier(0);  // no ds_read above the wait
#pragma unroll
                    for (int ib = 0; ib < 4; ++ib)
                        av[ib] = *(const bf16x8*)&Ab[(wr * 128 + ib * 32 + r5) * 64 + prd];
#pragma unroll
                    for (int jb = 0; jb < 2; ++jb)
                        bvv[jb] = *(const bf16x8*)&Bb[(wc * 64 + jb * 32 + r5) * 64 + prd];
                } else {
#pragma unroll
                    for (int ib = 0; ib < 4; ++ib)
                        av[ib] = *(const bf16x8*)&Ab[(wr * 128 + ib * 32 + r5) * 64 + prd];
#pragma unroll
                    for (int jb = 0; jb < 2; ++jb)
                        bvv[jb] = *(const bf16x8*)&Bb[(wc * 64 + jb * 32 + r5) * 64 + prd];
                    if (stg) STAGE(ks);
                }
                asm volatile("s_waitcnt lgkmcnt(0)" ::: "memory");
                __builtin_amdgcn_sched_barrier(0);  // rule 18: MFMA below the wait
                __builtin_amdgcn_s_setprio(1);
#pragma unroll
                for (int ib = 0; ib < 4; ++ib)
#pragma unroll
                    for (int jb = 0; jb < 2; ++jb)
                        acc[ib][jb] = __builtin_amdgcn_mfma_f32_32x32x16_bf16(
                            av[ib], bvv[jb], acc[ib][jb], 0, 0, 0);
                __builtin_amdgcn_s_setprio(0);
            }
            // tile end: all waves done reading buf[cur] before it is
            // overwritten next tile (STAGE(0) is issued after this join).
            __builtin_amdgcn_s_barrier();
        }

        // Epilogue: 32x32 C/D mapping col = lane&31, row = (reg&3)+8*(reg>>2)+4*half.
        // Runs after next-iter K0 was staged -> stores overlap prologue loads.
        {
            const int section = bn >> 2;                      // 0,1,2 (q/k/v)
            const int nloc0   = (bn & 3) * 256 + wc * 64;     // col within section
            const float* bias = (section == 0) ? bq : (section == 1) ? bk : bv;
            float* outsec = out + (size_t)section * (4u * 16u * 4096u * 64u);

#pragma unroll
            for (int jb = 0; jb < 2; ++jb) {
                int f = nloc0 + jb * 32 + r5;  // 0..1023 within section
                float bval = bias[f];
                int h = f >> 6, d = f & 63;
                size_t hb = (size_t)h * (4096u * 64u);
#pragma unroll
                for (int ib = 0; ib < 4; ++ib) {
                    int mbase = bm * 256 + wr * 128 + ib * 32 + 4 * half;
#pragma unroll
                    for (int reg = 0; reg < 16; ++reg) {
                        int m = mbase + (reg & 3) + 8 * (reg >> 2);
                        int b = m >> 12, s = m & 4095;
                        outsec[(size_t)b * (16u * 4096u * 64u) + hb + (size_t)s * 64u + d] =
                            acc[ib][jb][reg] + bval;
                    }
                }
            }
        }

        bm = bm2; bn = bn2; gA = gA2; gB = gB2;
    }
#undef STAGE
}

extern "C" void kernel_launch(void* const* d_in, const int* in_sizes, int n_in,
                              void* d_out, int out_size, void* d_ws, size_t ws_size,
                              hipStream_t stream) {
    const float* hs = (const float*)d_in[0];
    const float* Wq = (const float*)d_in[1];
    const float* bq = (const float*)d_in[2];
    const float* Wk = (const float*)d_in[3];
    const float* bk = (const float*)d_in[4];
    const float* Wv = (const float*)d_in[5];
    const float* bv = (const float*)d_in[6];
    float* out = (float*)d_out;

    unsigned short* Abf  = (unsigned short*)d_ws;            // 16384*1024 bf16 = 32 MiB
    unsigned short* Btbf = Abf + (size_t)M_TOT * K_TOT;      // 3072*1024  bf16 =  6 MiB

    convert_hidden<<<2048, 256, 0, stream>>>(hs, Abf, (M_TOT * K_TOT) / 4);
    convert_weights<<<dim3(16, 16, 3), 256, 0, stream>>>(Wq, Wk, Wv, Btbf);
    qkv_gemm<<<256, 512, 0, stream>>>(Abf, Btbf, bq, bk, bv, out);
}

// Round 3
// 370.440 us; speedup vs baseline: 1.0526x; 1.0046x over previous
//
#include <hip/hip_runtime.h>
#include <hip/hip_bf16.h>

// Fused QKV projection: qkv = hidden[16384,1024] @ Wqkv[1024,3072] + bias,
// scattered to q/k/v [4,16,4096,64] each, fp32 out.
// R6: deep-pipelined 256x256 persistent GEMM.
//  - staging granularity = K-half unit (A 256x32 + B 256x32, 4 loads/thread),
//    ring of 4 units per operand (128 KiB LDS total)
//  - unit u issued 2 phase-pairs (~2000 cyc) before its consuming wait ->
//    covers HBM latency; waits are counted vmcnt(8) (2 units in flight),
//    vmcnt(0) only at the very last pair of the last tile
//  - 1 barrier per pair (2 per K-tile); stage-issue directly after barrier
//    (slot it overwrites was fully read before that barrier)
//  - LDS swizzle for 64B row stride: slot = octet ^ ((row>>1)&3) -> 2-way
//    banks (free) on ds_read_b128; write side pre-swizzles global source
//  - persistent: 256 blocks x 3 tiles, 8bm x 4bn supertile per XCD (L2 reuse);
//    next tile's first 3 units prefetched before epilogue -> stores overlap

#define M_TOT 16384
#define N_TOT 3072
#define K_TOT 1024

typedef __bf16 bf16x8 __attribute__((ext_vector_type(8)));
typedef float f32x16 __attribute__((ext_vector_type(16)));

#define AS1(p) ((const __attribute__((address_space(1))) void*)(p))
#define AS3(p) ((__attribute__((address_space(3))) void*)(p))

__device__ __forceinline__ unsigned short f2bf(float f) {
    unsigned int u = __builtin_bit_cast(unsigned int, f);
    u += 0x7fffu + ((u >> 16) & 1u);
    return (unsigned short)(u >> 16);
}

// ---- kernel 1: hidden fp32 -> bf16, straight copy (row-major [16384][1024])
__global__ void convert_hidden(const float* __restrict__ x,
                               unsigned short* __restrict__ y, int n4) {
    int i = blockIdx.x * blockDim.x + threadIdx.x;
    int stride = gridDim.x * blockDim.x;
    for (; i < n4; i += stride) {
        float4 v = ((const float4*)x)[i];
        ushort4 o;
        o.x = f2bf(v.x); o.y = f2bf(v.y); o.z = f2bf(v.z); o.w = f2bf(v.w);
        ((ushort4*)y)[i] = o;
    }
}

// ---- kernel 2: W[k][f] fp32 -> Bt[wsel*1024 + f][k] bf16 (transpose), tiled 64x64
__global__ void convert_weights(const float* __restrict__ Wq,
                                const float* __restrict__ Wk,
                                const float* __restrict__ Wv,
                                unsigned short* __restrict__ Bt) {
    __shared__ unsigned short tile[64][65];
    const float* W = (blockIdx.z == 0) ? Wq : (blockIdx.z == 1) ? Wk : Wv;
    int k0 = blockIdx.y * 64;
    int f0 = blockIdx.x * 64;
    int tx = threadIdx.x & 63;
    int ty = threadIdx.x >> 6;  // 0..3
#pragma unroll
    for (int r = 0; r < 16; ++r) {
        int k = ty + r * 4;
        tile[k][tx] = f2bf(W[(size_t)(k0 + k) * 1024 + f0 + tx]);
    }
    __syncthreads();
#pragma unroll
    for (int r = 0; r < 16; ++r) {
        int fr = ty + r * 4;
        Bt[(size_t)(blockIdx.z * 1024 + f0 + fr) * 1024 + k0 + tx] = tile[tx][fr];
    }
}

// ---- kernel 3: persistent deep-pipelined 256x256 GEMM + scatter epilogue
// A [16384][1024] bf16 row-major, Bt [3072][1024] bf16 (W^T), out fp32.
// Unit u (u = 2*ktile + khalf): A rows[0,256) x k[koff,koff+32), same for B,
// koff = (u>>1)*64 + (u&1)*32. LDS unit: [256 rows][4 octets of 16B], row
// stride 64 B; octet o of row r at slot o ^ ((r>>1)&3).
__launch_bounds__(512, 2)
__global__ void qkv_gemm(const unsigned short* __restrict__ A,
                         const unsigned short* __restrict__ Bt,
                         const float* __restrict__ bq,
                         const float* __restrict__ bk,
                         const float* __restrict__ bv,
                         float* __restrict__ out) {
    __shared__ __align__(16) unsigned short As[4][8192];  // 4 x 16 KiB
    __shared__ __align__(16) unsigned short Bs[4][8192];  // 4 x 16 KiB

    const int tid  = threadIdx.x;
    const int wave = tid >> 6;
    const int lane = tid & 63;
    const int r5   = lane & 31;       // row within a 32-row MFMA block
    const int half = lane >> 5;       // k-octet select within a k-step
    const int sw2  = (r5 >> 1) & 3;   // read-side swizzle term

    // persistent mapping: 256 blocks x 3 iters -> 768 tiles (64bm x 12bn).
    // supertile = 8bm x 4bn (32 tiles); st = xcd*3 + i in [0,24); bijective.
    const int xcd = blockIdx.x & 7;
    const int j   = blockIdx.x >> 3;  // 0..31
    const int jm  = j & 7;            // bm within supertile
    const int jn  = j >> 3;           // bn within supertile

    const int wr = wave >> 2;   // 0..1  -> 128-row half of A
    const int wc = wave & 3;    // 0..3  -> 64-col quarter of B

    // staging: chunk c = q*512 + tid (q=0,1); row = c>>2 = q*128 + (tid>>2),
    // slot = tid&3; slot holds octet kq = slot ^ ((row>>1)&3).
    const int tr = tid >> 2;                            // 0..127
    const int kq = (tid & 3) ^ ((tid >> 3) & 3);        // source octet
    const size_t gOff = (size_t)tr * 1024 + (size_t)kq * 8;

    int st = xcd * 3;  // supertile for i=0
    int bm = (st & 7) * 8 + jm;
    int bn = (st >> 3) * 4 + jn;
    const unsigned short* gA = A  + (size_t)bm * 256 * 1024;
    const unsigned short* gB = Bt + (size_t)bn * 256 * 1024;

#define STAGE(slot, koff, bA, bB)                                               \
    do {                                                                        \
        const unsigned short* sA_ = (bA) + (size_t)(koff) + gOff;               \
        const unsigned short* sB_ = (bB) + (size_t)(koff) + gOff;               \
        unsigned short* dA_ = &As[(slot)][wave * 512];                          \
        unsigned short* dB_ = &Bs[(slot)][wave * 512];                          \
        __builtin_amdgcn_global_load_lds(AS1(sA_), AS3(dA_), 16, 0, 0);         \
        __builtin_amdgcn_global_load_lds(AS1(sA_ + 131072), AS3(dA_ + 4096),    \
                                         16, 0, 0);                             \
        __builtin_amdgcn_global_load_lds(AS1(sB_), AS3(dB_), 16, 0, 0);         \
        __builtin_amdgcn_global_load_lds(AS1(sB_ + 131072), AS3(dB_ + 4096),    \
                                         16, 0, 0);                             \
    } while (0)

// one phase-pair: 2 K-phases of 16 from unit in ring slot `slotc`
#define PAIR(slotc)                                                             \
    do {                                                                        \
        const unsigned short* Au = &As[(slotc)][0];                             \
        const unsigned short* Bu = &Bs[(slotc)][0];                             \
        _Pragma("unroll") for (int ks = 0; ks < 2; ++ks) {                      \
            bf16x8 av[4], bvv[2];                                               \
            const int po = ((ks * 2 + half) ^ sw2) * 8;                         \
            _Pragma("unroll") for (int ib = 0; ib < 4; ++ib)                    \
                av[ib] = *(const bf16x8*)&Au[(wr * 128 + ib * 32 + r5) * 32 + po]; \
            _Pragma("unroll") for (int jb = 0; jb < 2; ++jb)                    \
                bvv[jb] = *(const bf16x8*)&Bu[(wc * 64 + jb * 32 + r5) * 32 + po]; \
            asm volatile("s_waitcnt lgkmcnt(0)" ::: "memory");                  \
            __builtin_amdgcn_sched_barrier(0);                                  \
            __builtin_amdgcn_s_setprio(1);                                      \
            _Pragma("unroll") for (int ib = 0; ib < 4; ++ib)                    \
                _Pragma("unroll") for (int jb = 0; jb < 2; ++jb)                \
                    acc[ib][jb] = __builtin_amdgcn_mfma_f32_32x32x16_bf16(      \
                        av[ib], bvv[jb], acc[ib][jb], 0, 0, 0);                 \
            __builtin_amdgcn_s_setprio(0);                                      \
        }                                                                       \
    } while (0)

#define UKOFF(u) ((size_t)(((u) >> 1) * 64 + ((u) & 1) * 32))

    // prologue: issue units 0,1,2 of iter 0 (12 loads/thread)
    STAGE(0, UKOFF(0), gA, gB);
    STAGE(1, UKOFF(1), gA, gB);
    STAGE(2, UKOFF(2), gA, gB);

    for (int i = 0; i < 3; ++i) {
        // next-iter tile (its first 3 units are staged during t=14/15)
        int bm2 = bm, bn2 = bn;
        const unsigned short *gA2 = gA, *gB2 = gB;
        if (i < 2) {
            int st2 = xcd * 3 + i + 1;
            bm2 = (st2 & 7) * 8 + jm;
            bn2 = (st2 >> 3) * 4 + jn;
            gA2 = A  + (size_t)bm2 * 256 * 1024;
            gB2 = Bt + (size_t)bn2 * 256 * 1024;
        }
        const bool lastIter = (i == 2);

        f32x16 acc[4][2] = {};

#pragma unroll 2
        for (int t = 0; t < 16; ++t) {
            // ---- pair 0: consume unit 2t; issue unit 2t+3 ----
            if (lastIter && t == 15)
                asm volatile("s_waitcnt vmcnt(4)" ::: "memory");
            else
                asm volatile("s_waitcnt vmcnt(8)" ::: "memory");
            __builtin_amdgcn_s_barrier();
            __builtin_amdgcn_sched_barrier(0);  // no ds_read above the wait
            {
                const int u = 2 * t + 3;
                if (u < 32)        STAGE(u & 3, UKOFF(u), gA, gB);
                else if (i < 2)    STAGE((u - 32) & 3, UKOFF(u - 32), gA2, gB2);
            }
            PAIR((2 * t) & 3);

            // ---- pair 1: consume unit 2t+1; issue unit 2t+4 ----
            if (lastIter && t == 15)
                asm volatile("s_waitcnt vmcnt(0)" ::: "memory");
            else
                asm volatile("s_waitcnt vmcnt(8)" ::: "memory");
            __builtin_amdgcn_s_barrier();
            __builtin_amdgcn_sched_barrier(0);
            {
                const int u = 2 * t + 4;
                if (u < 32)        STAGE(u & 3, UKOFF(u), gA, gB);
                else if (i < 2)    STAGE((u - 32) & 3, UKOFF(u - 32), gA2, gB2);
            }
            PAIR((2 * t + 1) & 3);
        }

        // Epilogue: 32x32 C/D mapping col = lane&31, row = (reg&3)+8*(reg>>2)+4*half.
        // Next-iter units 0..2 already in flight -> stores overlap prologue.
        {
            const int section = bn >> 2;                      // 0,1,2 (q/k/v)
            const int nloc0   = (bn & 3) * 256 + wc * 64;     // col within section
            const float* bias = (section == 0) ? bq : (section == 1) ? bk : bv;
            float* outsec = out + (size_t)section * (4u * 16u * 4096u * 64u);

#pragma unroll
            for (int jb = 0; jb < 2; ++jb) {
                int f = nloc0 + jb * 32 + r5;  // 0..1023 within section
                float bval = bias[f];
                int h = f >> 6, d = f & 63;
                size_t hb = (size_t)h * (4096u * 64u);
#pragma unroll
                for (int ib = 0; ib < 4; ++ib) {
                    int mbase = bm * 256 + wr * 128 + ib * 32 + 4 * half;
#pragma unroll
                    for (int reg = 0; reg < 16; ++reg) {
                        int m = mbase + (reg & 3) + 8 * (reg >> 2);
                        int b = m >> 12, s = m & 4095;
                        outsec[(size_t)b * (16u * 4096u * 64u) + hb + (size_t)s * 64u + d] =
                            acc[ib][jb][reg] + bval;
                    }
                }
            }
        }

        bm = bm2; bn = bn2; gA = gA2; gB = gB2;
    }
#undef STAGE
#undef PAIR
#undef UKOFF
}

extern "C" void kernel_launch(void* const* d_in, const int* in_sizes, int n_in,
                              void* d_out, int out_size, void* d_ws, size_t ws_size,
                              hipStream_t stream) {
    const float* hs = (const float*)d_in[0];
    const float* Wq = (const float*)d_in[1];
    const float* bq = (const float*)d_in[2];
    const float* Wk = (const float*)d_in[3];
    const float* bk = (const float*)d_in[4];
    const float* Wv = (const float*)d_in[5];
    const float* bv = (const float*)d_in[6];
    float* out = (float*)d_out;

    unsigned short* Abf  = (unsigned short*)d_ws;            // 16384*1024 bf16 = 32 MiB
    unsigned short* Btbf = Abf + (size_t)M_TOT * K_TOT;      // 3072*1024  bf16 =  6 MiB

    convert_hidden<<<2048, 256, 0, stream>>>(hs, Abf, (M_TOT * K_TOT) / 4);
    convert_weights<<<dim3(16, 16, 3), 256, 0, stream>>>(Wq, Wk, Wv, Btbf);
    qkv_gemm<<<256, 512, 0, stream>>>(Abf, Btbf, bq, bk, bv, out);
}